// Round 10
// baseline (380.596 us; speedup 1.0000x reference)
//
// LinformerAttention MI355X pipeline — r10: gemm_qattn LDS 34816->32768
// (Qtile stride 128, single per-wave P slab) to lift occupancy of the
// latency-bound fused attention epilogue. Math identical to r9.
#include <hip/hip_runtime.h>

typedef __bf16 bf16x8 __attribute__((ext_vector_type(8)));
typedef float f32x4 __attribute__((ext_vector_type(4)));

#define AS1 __attribute__((address_space(1)))
#define AS3 __attribute__((address_space(3)))

__device__ __forceinline__ void gload_lds16(const void* g, void* l) {
    __builtin_amdgcn_global_load_lds((const AS1 void*)g, (AS3 void*)l, 16, 0, 0);
}

__device__ __forceinline__ unsigned short f2bf(float f) {
    unsigned u = __builtin_bit_cast(unsigned, f);
    u += 0x7fffu + ((u >> 16) & 1u);
    return (unsigned short)(u >> 16);
}

__device__ __forceinline__ float bf2f(unsigned short u) {
    return __builtin_bit_cast(float, (unsigned)u << 16);
}

// ---------------- fused fp32->bf16 conversions (single launch) ----------------
// ids [0,4096): x -> xb (row-major) and xT (transposed) via 64x64 LDS tiles
// ids [4096,7168): Wq|Wk|Wv -> Wb ; ids [7168,15360): E -> Eb
__global__ __launch_bounds__(256) void fused_cvt(
        const float* __restrict__ x, const float* __restrict__ Wq,
        const float* __restrict__ Wk, const float* __restrict__ Wv,
        const float* __restrict__ E,
        unsigned short* __restrict__ xb, unsigned short* __restrict__ xT,
        unsigned short* __restrict__ Wb, unsigned short* __restrict__ Eb) {
    __shared__ unsigned short tile[64][68];   // pad 68: breaks bank alignment on transpose
    const int id = blockIdx.x, t = threadIdx.x;
    if (id < 4096) {
        const int cx = id & 15, ly = (id >> 4) & 63, b = id >> 10;
        const int l0 = ly * 64, c0 = cx * 64;
        const int r = t >> 4, c4 = t & 15;
#pragma unroll
        for (int p = 0; p < 4; p++) {
            int row = p * 16 + r;
            const float4 v = *(const float4*)&x[(size_t)(b * 4096 + l0 + row) * 1024 + c0 + c4 * 4];
            ushort4 o;
            o.x = f2bf(v.x); o.y = f2bf(v.y); o.z = f2bf(v.z); o.w = f2bf(v.w);
            *(ushort4*)&xb[(size_t)(b * 4096 + l0 + row) * 1024 + c0 + c4 * 4] = o;
            tile[c4 * 4 + 0][row] = o.x;
            tile[c4 * 4 + 1][row] = o.y;
            tile[c4 * 4 + 2][row] = o.z;
            tile[c4 * 4 + 3][row] = o.w;
        }
        __syncthreads();
#pragma unroll
        for (int p = 0; p < 4; p++) {
            int c = p * 16 + r;
            ushort4 o = *(const ushort4*)&tile[c][c4 * 4];
            *(ushort4*)&xT[(size_t)(b * 1024 + c0 + c) * 4096 + l0 + c4 * 4] = o;
        }
    } else if (id < 7168) {
        const int wi = id - 4096, which = wi >> 10;
        const int i = (wi & 1023) * 256 + t;
        const float* src = (which == 0) ? Wq : (which == 1 ? Wk : Wv);
        float4 v = reinterpret_cast<const float4*>(src)[i];
        ushort4 o;
        o.x = f2bf(v.x); o.y = f2bf(v.y); o.z = f2bf(v.z); o.w = f2bf(v.w);
        reinterpret_cast<ushort4*>(Wb + (size_t)which * 1048576)[i] = o;
    } else {
        const int i = (id - 7168) * 256 + t;
        float4 v = reinterpret_cast<const float4*>(E)[i];
        ushort4 o;
        o.x = f2bf(v.x); o.y = f2bf(v.y); o.z = f2bf(v.z); o.w = f2bf(v.w);
        reinterpret_cast<ushort4*>(Eb)[i] = o;
    }
}

// ---------------- Ex = E @ x (per batch), m97 skeleton, K=4096 ----------------
__global__ __launch_bounds__(256) void gemm_ex(
        const unsigned short* __restrict__ Eb, const unsigned short* __restrict__ xTb,
        unsigned short* __restrict__ Exb) {
    __shared__ unsigned short lA[2 * 128 * 32];
    __shared__ unsigned short lB[2 * 128 * 32];
    const int tid = threadIdx.x, w = tid >> 6, lane = tid & 63;
    const int m0 = blockIdx.y * 128, n0 = blockIdx.x * 128;
    const unsigned short* xT = xTb + (size_t)blockIdx.z * 1024 * 4096;
    unsigned short* Ex = Exb + (size_t)blockIdx.z * 2048 * 1024;
    const int srow = lane >> 2, scol = (lane & 3) * 8;
    const int l15 = lane & 15, quad = lane >> 4;
    const int wm = w >> 1, wn = w & 1;
    f32x4 acc[4][4] = {};
    for (int k0 = 0; k0 < 4096; k0 += 64) {
        __syncthreads();
#pragma unroll
        for (int s = 0; s < 2; s++) {
#pragma unroll
            for (int i = 0; i < 2; i++) {
                int t = w * 2 + i;
                gload_lds16(Eb + (size_t)(m0 + t * 16 + srow) * 4096 + k0 + s * 32 + scol,
                            (char*)lA + (s * 8192 + t * 1024));
                gload_lds16(xT + (size_t)(n0 + t * 16 + srow) * 4096 + k0 + s * 32 + scol,
                            (char*)lB + (s * 8192 + t * 1024));
            }
        }
        __syncthreads();
#pragma unroll
        for (int s = 0; s < 2; s++) {
            bf16x8 af[4], bfr[4];
#pragma unroll
            for (int mi = 0; mi < 4; mi++)
                af[mi] = *(const bf16x8*)&lA[(s * 128 + wm * 64 + mi * 16 + l15) * 32 + quad * 8];
#pragma unroll
            for (int ni = 0; ni < 4; ni++)
                bfr[ni] = *(const bf16x8*)&lB[(s * 128 + wn * 64 + ni * 16 + l15) * 32 + quad * 8];
#pragma unroll
            for (int mi = 0; mi < 4; mi++)
#pragma unroll
                for (int ni = 0; ni < 4; ni++)
                    acc[mi][ni] = __builtin_amdgcn_mfma_f32_16x16x32_bf16(af[mi], bfr[ni],
                                                                          acc[mi][ni], 0, 0, 0);
        }
    }
#pragma unroll
    for (int ni = 0; ni < 4; ni++) {
        int col = n0 + wn * 64 + ni * 16 + l15;
#pragma unroll
        for (int mi = 0; mi < 4; mi++) {
            int row = m0 + wm * 64 + mi * 16 + quad * 4;
#pragma unroll
            for (int r = 0; r < 4; r++)
                Ex[(size_t)(row + r) * 1024 + col] = f2bf(acc[mi][ni][r]);
        }
    }
}

// ---------------- Kp / VpT per (b,h), 4-way k-split, double-buffered ----------------
__global__ __launch_bounds__(256) void kpvp4(
        const unsigned short* __restrict__ Exb, const unsigned short* __restrict__ Wb,
        const unsigned short* __restrict__ Eb, const float* __restrict__ bk,
        const float* __restrict__ bv,
        unsigned short* __restrict__ Kpb, unsigned short* __restrict__ VpTb) {
    __shared__ unsigned short Exsh[2 * 32 * 32];
    __shared__ unsigned short Wksh[2 * 64 * 32];
    __shared__ unsigned short Wvsh[2 * 64 * 32];
    __shared__ float EsumSh[32];
    const int tid = threadIdx.x, w = tid >> 6, lane = tid & 63;
    const int l15 = lane & 15, quad = lane >> 4;
    const int srow = lane >> 2, scol = (lane & 3) * 8;
    const int bh = blockIdx.x & 63, q = blockIdx.x >> 6;
    const int b = bh >> 4, h = bh & 15;
    const unsigned short* Ex = Exb + ((size_t)b * 2048 + h * 128 + q * 32) * 1024;
    const unsigned short* Wk = Wb + 1048576 + (size_t)h * 64 * 1024;
    const unsigned short* Wv = Wb + 2097152 + (size_t)h * 64 * 1024;
    for (int r = w; r < 32; r += 4) {
        const unsigned short* er = Eb + ((size_t)(h * 128 + q * 32 + r)) * 4096;
        float s = 0.f;
#pragma unroll
        for (int i = 0; i < 8; i++) {
            ushort4 a = *(const ushort4*)&er[i * 512 + lane * 8];
            ushort4 b2 = *(const ushort4*)&er[i * 512 + lane * 8 + 4];
            s += bf2f(a.x) + bf2f(a.y) + bf2f(a.z) + bf2f(a.w);
            s += bf2f(b2.x) + bf2f(b2.y) + bf2f(b2.z) + bf2f(b2.w);
        }
#pragma unroll
        for (int off = 32; off >= 1; off >>= 1) s += __shfl_xor(s, off, 64);
        if (lane == 0) EsumSh[r] = s;
    }
    f32x4 accK[4] = {};
    f32x4 accV[2][2] = {};
    auto STAGE = [&](int t, int s) {
        const int c0 = t * 32;
        if (w < 2)
            gload_lds16(Ex + (size_t)(w * 16 + srow) * 1024 + c0 + scol,
                        (char*)Exsh + s * 2048 + w * 1024);
        gload_lds16(Wk + (size_t)(w * 16 + srow) * 1024 + c0 + scol,
                    (char*)Wksh + s * 4096 + w * 1024);
        gload_lds16(Wv + (size_t)(w * 16 + srow) * 1024 + c0 + scol,
                    (char*)Wvsh + s * 4096 + w * 1024);
    };
    auto COMPUTE = [&](int s) {
        if (w < 2) {
            bf16x8 af = *(const bf16x8*)&Exsh[s * 1024 + (w * 16 + l15) * 32 + quad * 8];
#pragma unroll
            for (int nt = 0; nt < 4; nt++) {
                bf16x8 bb = *(const bf16x8*)&Wksh[s * 2048 + (nt * 16 + l15) * 32 + quad * 8];
                accK[nt] = __builtin_amdgcn_mfma_f32_16x16x32_bf16(af, bb, accK[nt], 0, 0, 0);
            }
        } else {
            bf16x8 av[2], be[2];
#pragma unroll
            for (int mi = 0; mi < 2; mi++)
                av[mi] = *(const bf16x8*)&Wvsh[s * 2048 + (((w - 2) * 2 + mi) * 16 + l15) * 32 + quad * 8];
#pragma unroll
            for (int n = 0; n < 2; n++)
                be[n] = *(const bf16x8*)&Exsh[s * 1024 + (n * 16 + l15) * 32 + quad * 8];
#pragma unroll
            for (int mi = 0; mi < 2; mi++)
#pragma unroll
                for (int n = 0; n < 2; n++)
                    accV[mi][n] = __builtin_amdgcn_mfma_f32_16x16x32_bf16(av[mi], be[n],
                                                                          accV[mi][n], 0, 0, 0);
        }
    };
    STAGE(0, 0);
    __syncthreads();
    for (int t = 0; t < 31; ++t) {
        STAGE(t + 1, (t + 1) & 1);
        COMPUTE(t & 1);
        __syncthreads();
    }
    COMPUTE(1);
    unsigned short* Kp = Kpb + (size_t)bh * 128 * 64;
    unsigned short* VpT = VpTb + (size_t)bh * 64 * 128;
    if (w < 2) {
#pragma unroll
        for (int nt = 0; nt < 4; nt++) {
            int col = nt * 16 + l15;
            float bkv = bk[h * 64 + col];
#pragma unroll
            for (int r = 0; r < 4; r++) {
                int krow = w * 16 + quad * 4 + r;
                Kp[(q * 32 + krow) * 64 + col] = f2bf(accK[nt][r] + EsumSh[krow] * bkv);
            }
        }
    } else {
#pragma unroll
        for (int mi = 0; mi < 2; mi++)
#pragma unroll
            for (int n = 0; n < 2; n++) {
                int kcol = n * 16 + l15;
                float es = EsumSh[kcol];
#pragma unroll
                for (int r = 0; r < 4; r++) {
                    int d = ((w - 2) * 2 + mi) * 16 + quad * 4 + r;
                    VpT[d * 128 + q * 32 + kcol] = f2bf(accV[mi][n][r] + es * bv[h * 64 + d]);
                }
            }
    }
}

// ---------------- fused Q projection + attention ----------------
// Per block: 128x128 Q tile (128 seq rows x heads {2*bx, 2*bx+1}), K=1024 m97 loop.
// Each wave (wm,wn) owns a 64-row x 1-head sub-tile = an independent attention unit.
// LDS = 32768 B exactly (occupancy: 5 blocks/CU by LDS, 4 waves each):
//   phase 1: staging lA|lB (32768 B)
//   phase 2: Qtile[128][128] (32768 B; stride-128 bank conflict is 8 one-time reads/wave)
//   phase 3: 4 per-wave P slabs [16][136] (8704 shorts; per-wave private, same-wave
//            LDS ops are in-order so no double-buffer / no barriers needed)
__global__ __launch_bounds__(256) void gemm_qattn(
        const unsigned short* __restrict__ xb, const unsigned short* __restrict__ Wb,
        const float* __restrict__ bq,
        const unsigned short* __restrict__ Kpb, const unsigned short* __restrict__ VpTb,
        float* __restrict__ out) {
    __shared__ __align__(16) unsigned short smem[16384];   // 32,768 B
    unsigned short* lA = smem;
    unsigned short* lB = smem + 8192;
    const int tid = threadIdx.x, w = tid >> 6, lane = tid & 63;
    const int m0 = blockIdx.y * 128, n0 = blockIdx.x * 128;
    const int srow = lane >> 2, scol = (lane & 3) * 8;
    const int l15 = lane & 15, quad = lane >> 4;
    const int wm = w >> 1, wn = w & 1;
    f32x4 acc[4][4] = {};
    for (int k0 = 0; k0 < 1024; k0 += 64) {
        __syncthreads();
#pragma unroll
        for (int s = 0; s < 2; s++) {
#pragma unroll
            for (int i = 0; i < 2; i++) {
                int t = w * 2 + i;
                gload_lds16(xb + (size_t)(m0 + t * 16 + srow) * 1024 + k0 + s * 32 + scol,
                            (char*)lA + (s * 8192 + t * 1024));
                gload_lds16(Wb + (size_t)(n0 + t * 16 + srow) * 1024 + k0 + s * 32 + scol,
                            (char*)lB + (s * 8192 + t * 1024));
            }
        }
        __syncthreads();
#pragma unroll
        for (int s = 0; s < 2; s++) {
            bf16x8 af[4], bfr[4];
#pragma unroll
            for (int mi = 0; mi < 4; mi++)
                af[mi] = *(const bf16x8*)&lA[(s * 128 + wm * 64 + mi * 16 + l15) * 32 + quad * 8];
#pragma unroll
            for (int ni = 0; ni < 4; ni++)
                bfr[ni] = *(const bf16x8*)&lB[(s * 128 + wn * 64 + ni * 16 + l15) * 32 + quad * 8];
#pragma unroll
            for (int mi = 0; mi < 4; mi++)
#pragma unroll
                for (int ni = 0; ni < 4; ni++)
                    acc[mi][ni] = __builtin_amdgcn_mfma_f32_16x16x32_bf16(af[mi], bfr[ni],
                                                                          acc[mi][ni], 0, 0, 0);
        }
    }
    __syncthreads();   // staging dead; smem becomes Qtile[128][128]
    // Q tile (bias added) -> LDS, C layout (row=quad*4+r, col=l15)
#pragma unroll
    for (int ni = 0; ni < 4; ni++) {
        int lc = wn * 64 + ni * 16 + l15;
        float bias_v = bq[n0 + lc];
#pragma unroll
        for (int mi = 0; mi < 4; mi++) {
            int lr = wm * 64 + mi * 16 + quad * 4;
#pragma unroll
            for (int r = 0; r < 4; r++)
                smem[(lr + r) * 128 + lc] = f2bf(acc[mi][ni][r] + bias_v);
        }
    }
    __syncthreads();
    // per-wave Q A-fragments: rows wm*64+rt*16+l15, head cols wn*64 + ds*32 + quad*8
    bf16x8 aq[4][2];
#pragma unroll
    for (int rt = 0; rt < 4; rt++)
#pragma unroll
        for (int ds = 0; ds < 2; ds++)
            aq[rt][ds] = *(const bf16x8*)&smem[(wm * 64 + rt * 16 + l15) * 128 +
                                               wn * 64 + ds * 32 + quad * 8];
    __syncthreads();   // all waves got Q frags; smem becomes per-wave P slabs
    const int b = m0 >> 12;
    const int h = blockIdx.x * 2 + wn;
    const int lbase = (m0 & 4095) + wm * 64;
    const unsigned short* Kp = Kpb + (size_t)(b * 16 + h) * 128 * 64;
    const unsigned short* Vp = VpTb + (size_t)(b * 16 + h) * 64 * 128;
    const float scale = 0.125f;
    unsigned short* slab = smem + w * 2176;   // per-wave private [16][136]
    f32x4 acco[4][4] = {};   // [rt][nt]
#pragma unroll
    for (int rt = 0; rt < 4; rt++) {
        // QK^T: 16 rows x 128 k
        f32x4 sc[8];
#pragma unroll
        for (int kt = 0; kt < 8; kt++) {
            const unsigned short* kr = Kp + (size_t)(kt * 16 + l15) * 64;
            bf16x8 b0 = *(const bf16x8*)&kr[quad * 8];
            bf16x8 b1 = *(const bf16x8*)&kr[32 + quad * 8];
            f32x4 a = {};
            a = __builtin_amdgcn_mfma_f32_16x16x32_bf16(aq[rt][0], b0, a, 0, 0, 0);
            a = __builtin_amdgcn_mfma_f32_16x16x32_bf16(aq[rt][1], b1, a, 0, 0, 0);
            sc[kt] = a;
        }
        // softmax over 128 cols (kt regs x l15 lanes); in-place into sc
#pragma unroll
        for (int r = 0; r < 4; r++) {
            float m = -1e30f;
#pragma unroll
            for (int kt = 0; kt < 8; kt++) m = fmaxf(m, sc[kt][r]);
#pragma unroll
            for (int off = 8; off >= 1; off >>= 1) m = fmaxf(m, __shfl_xor(m, off, 64));
            float s = 0.f;
#pragma unroll
            for (int kt = 0; kt < 8; kt++) {
                float e = __expf(scale * (sc[kt][r] - m));
                sc[kt][r] = e;
                s += e;
            }
#pragma unroll
            for (int off = 8; off >= 1; off >>= 1) s += __shfl_xor(s, off, 64);
            float rinv = 1.0f / s;
#pragma unroll
            for (int kt = 0; kt < 8; kt++) sc[kt][r] *= rinv;
        }
        // P -> per-wave slab (C layout) -> A-fragments
#pragma unroll
        for (int kt = 0; kt < 8; kt++)
#pragma unroll
            for (int r = 0; r < 4; r++)
                slab[(quad * 4 + r) * 136 + kt * 16 + l15] = f2bf(sc[kt][r]);
        bf16x8 ap[4];
#pragma unroll
        for (int t = 0; t < 4; t++)
            ap[t] = *(const bf16x8*)&slab[l15 * 136 + t * 32 + quad * 8];
        // PV: 16 rows x 64 d
#pragma unroll
        for (int nt = 0; nt < 4; nt++) {
            const unsigned short* vr = Vp + (size_t)(nt * 16 + l15) * 128;
#pragma unroll
            for (int t = 0; t < 4; t++) {
                bf16x8 bv = *(const bf16x8*)&vr[t * 32 + quad * 8];
                acco[rt][nt] = __builtin_amdgcn_mfma_f32_16x16x32_bf16(ap[t], bv,
                                                                       acco[rt][nt], 0, 0, 0);
            }
        }
    }
#pragma unroll
    for (int rt = 0; rt < 4; rt++)
#pragma unroll
        for (int nt = 0; nt < 4; nt++) {
            int col = h * 64 + nt * 16 + l15;
#pragma unroll
            for (int r = 0; r < 4; r++)
                out[(size_t)(b * 4096 + lbase + rt * 16 + quad * 4 + r) * 1024 + col] =
                    acco[rt][nt][r];
        }
}

extern "C" void kernel_launch(void* const* d_in, const int* in_sizes, int n_in,
                              void* d_out, int out_size, void* d_ws, size_t ws_size,
                              hipStream_t stream) {
    const float* x  = (const float*)d_in[0];
    const float* Wq = (const float*)d_in[1];
    const float* bq = (const float*)d_in[2];
    const float* Wk = (const float*)d_in[3];
    const float* bk = (const float*)d_in[4];
    const float* Wv = (const float*)d_in[5];
    const float* bv = (const float*)d_in[6];
    const float* E  = (const float*)d_in[7];
    float* out = (float*)d_out;
    char* ws = (char*)d_ws;

    // Alias-free workspace: every byte has exactly one value per call, identical
    // across calls — safe under overlapped graph replays.
    unsigned short* xb   = (unsigned short*)(ws);              // 33,554,432 [b*4096][1024]
    unsigned short* xTb  = (unsigned short*)(ws + 33554432);   // 33,554,432 [b][1024][4096]
    unsigned short* Wb   = (unsigned short*)(ws + 67108864);   //  6,291,456 (Wq|Wk|Wv)
    unsigned short* Eb   = (unsigned short*)(ws + 106954752);  // 16,777,216 [2048][4096]
    unsigned short* Exb  = (unsigned short*)(ws + 123731968);  // 16,777,216 [b][2048][1024]
    unsigned short* Kpb  = (unsigned short*)(ws + 140509184);  //  1,048,576 [bh][128][64]
    unsigned short* VpTb = (unsigned short*)(ws + 141557760);  //  1,048,576 [bh][64][128]
    if (ws_size < 142606336) return;                           // total = 142,606,336

    fused_cvt<<<15360, 256, 0, stream>>>(x, Wq, Wk, Wv, E, xb, xTb, Wb, Eb);
    gemm_ex<<<dim3(8, 16, 4), 256, 0, stream>>>(Eb, xTb, Exb);
    kpvp4<<<256, 256, 0, stream>>>(Exb, Wb, Eb, bk, bv, Kpb, VpTb);
    gemm_qattn<<<dim3(8, 128), 256, 0, stream>>>(xb, Wb, bq, Kpb, VpTb, out);
}

// Round 11
// 367.766 us; speedup vs baseline: 1.0349x; 1.0349x over previous
//
// LinformerAttention MI355X pipeline — r11: hoist Kp B-fragments out of the
// rt-loop in gemm_qattn (they are rt-invariant; removes 48 redundant global
// loads + their latency from the serial epilogue chain). Math identical.
#include <hip/hip_runtime.h>

typedef __bf16 bf16x8 __attribute__((ext_vector_type(8)));
typedef float f32x4 __attribute__((ext_vector_type(4)));

#define AS1 __attribute__((address_space(1)))
#define AS3 __attribute__((address_space(3)))

__device__ __forceinline__ void gload_lds16(const void* g, void* l) {
    __builtin_amdgcn_global_load_lds((const AS1 void*)g, (AS3 void*)l, 16, 0, 0);
}

__device__ __forceinline__ unsigned short f2bf(float f) {
    unsigned u = __builtin_bit_cast(unsigned, f);
    u += 0x7fffu + ((u >> 16) & 1u);
    return (unsigned short)(u >> 16);
}

__device__ __forceinline__ float bf2f(unsigned short u) {
    return __builtin_bit_cast(float, (unsigned)u << 16);
}

// ---------------- fused fp32->bf16 conversions (single launch) ----------------
// ids [0,4096): x -> xb (row-major) and xT (transposed) via 64x64 LDS tiles
// ids [4096,7168): Wq|Wk|Wv -> Wb ; ids [7168,15360): E -> Eb
__global__ __launch_bounds__(256) void fused_cvt(
        const float* __restrict__ x, const float* __restrict__ Wq,
        const float* __restrict__ Wk, const float* __restrict__ Wv,
        const float* __restrict__ E,
        unsigned short* __restrict__ xb, unsigned short* __restrict__ xT,
        unsigned short* __restrict__ Wb, unsigned short* __restrict__ Eb) {
    __shared__ unsigned short tile[64][68];   // pad 68: breaks bank alignment on transpose
    const int id = blockIdx.x, t = threadIdx.x;
    if (id < 4096) {
        const int cx = id & 15, ly = (id >> 4) & 63, b = id >> 10;
        const int l0 = ly * 64, c0 = cx * 64;
        const int r = t >> 4, c4 = t & 15;
#pragma unroll
        for (int p = 0; p < 4; p++) {
            int row = p * 16 + r;
            const float4 v = *(const float4*)&x[(size_t)(b * 4096 + l0 + row) * 1024 + c0 + c4 * 4];
            ushort4 o;
            o.x = f2bf(v.x); o.y = f2bf(v.y); o.z = f2bf(v.z); o.w = f2bf(v.w);
            *(ushort4*)&xb[(size_t)(b * 4096 + l0 + row) * 1024 + c0 + c4 * 4] = o;
            tile[c4 * 4 + 0][row] = o.x;
            tile[c4 * 4 + 1][row] = o.y;
            tile[c4 * 4 + 2][row] = o.z;
            tile[c4 * 4 + 3][row] = o.w;
        }
        __syncthreads();
#pragma unroll
        for (int p = 0; p < 4; p++) {
            int c = p * 16 + r;
            ushort4 o = *(const ushort4*)&tile[c][c4 * 4];
            *(ushort4*)&xT[(size_t)(b * 1024 + c0 + c) * 4096 + l0 + c4 * 4] = o;
        }
    } else if (id < 7168) {
        const int wi = id - 4096, which = wi >> 10;
        const int i = (wi & 1023) * 256 + t;
        const float* src = (which == 0) ? Wq : (which == 1 ? Wk : Wv);
        float4 v = reinterpret_cast<const float4*>(src)[i];
        ushort4 o;
        o.x = f2bf(v.x); o.y = f2bf(v.y); o.z = f2bf(v.z); o.w = f2bf(v.w);
        reinterpret_cast<ushort4*>(Wb + (size_t)which * 1048576)[i] = o;
    } else {
        const int i = (id - 7168) * 256 + t;
        float4 v = reinterpret_cast<const float4*>(E)[i];
        ushort4 o;
        o.x = f2bf(v.x); o.y = f2bf(v.y); o.z = f2bf(v.z); o.w = f2bf(v.w);
        reinterpret_cast<ushort4*>(Eb)[i] = o;
    }
}

// ---------------- Ex = E @ x (per batch), m97 skeleton, K=4096 ----------------
__global__ __launch_bounds__(256) void gemm_ex(
        const unsigned short* __restrict__ Eb, const unsigned short* __restrict__ xTb,
        unsigned short* __restrict__ Exb) {
    __shared__ unsigned short lA[2 * 128 * 32];
    __shared__ unsigned short lB[2 * 128 * 32];
    const int tid = threadIdx.x, w = tid >> 6, lane = tid & 63;
    const int m0 = blockIdx.y * 128, n0 = blockIdx.x * 128;
    const unsigned short* xT = xTb + (size_t)blockIdx.z * 1024 * 4096;
    unsigned short* Ex = Exb + (size_t)blockIdx.z * 2048 * 1024;
    const int srow = lane >> 2, scol = (lane & 3) * 8;
    const int l15 = lane & 15, quad = lane >> 4;
    const int wm = w >> 1, wn = w & 1;
    f32x4 acc[4][4] = {};
    for (int k0 = 0; k0 < 4096; k0 += 64) {
        __syncthreads();
#pragma unroll
        for (int s = 0; s < 2; s++) {
#pragma unroll
            for (int i = 0; i < 2; i++) {
                int t = w * 2 + i;
                gload_lds16(Eb + (size_t)(m0 + t * 16 + srow) * 4096 + k0 + s * 32 + scol,
                            (char*)lA + (s * 8192 + t * 1024));
                gload_lds16(xT + (size_t)(n0 + t * 16 + srow) * 4096 + k0 + s * 32 + scol,
                            (char*)lB + (s * 8192 + t * 1024));
            }
        }
        __syncthreads();
#pragma unroll
        for (int s = 0; s < 2; s++) {
            bf16x8 af[4], bfr[4];
#pragma unroll
            for (int mi = 0; mi < 4; mi++)
                af[mi] = *(const bf16x8*)&lA[(s * 128 + wm * 64 + mi * 16 + l15) * 32 + quad * 8];
#pragma unroll
            for (int ni = 0; ni < 4; ni++)
                bfr[ni] = *(const bf16x8*)&lB[(s * 128 + wn * 64 + ni * 16 + l15) * 32 + quad * 8];
#pragma unroll
            for (int mi = 0; mi < 4; mi++)
#pragma unroll
                for (int ni = 0; ni < 4; ni++)
                    acc[mi][ni] = __builtin_amdgcn_mfma_f32_16x16x32_bf16(af[mi], bfr[ni],
                                                                          acc[mi][ni], 0, 0, 0);
        }
    }
#pragma unroll
    for (int ni = 0; ni < 4; ni++) {
        int col = n0 + wn * 64 + ni * 16 + l15;
#pragma unroll
        for (int mi = 0; mi < 4; mi++) {
            int row = m0 + wm * 64 + mi * 16 + quad * 4;
#pragma unroll
            for (int r = 0; r < 4; r++)
                Ex[(size_t)(row + r) * 1024 + col] = f2bf(acc[mi][ni][r]);
        }
    }
}

// ---------------- Kp / VpT per (b,h), 4-way k-split, double-buffered ----------------
__global__ __launch_bounds__(256) void kpvp4(
        const unsigned short* __restrict__ Exb, const unsigned short* __restrict__ Wb,
        const unsigned short* __restrict__ Eb, const float* __restrict__ bk,
        const float* __restrict__ bv,
        unsigned short* __restrict__ Kpb, unsigned short* __restrict__ VpTb) {
    __shared__ unsigned short Exsh[2 * 32 * 32];
    __shared__ unsigned short Wksh[2 * 64 * 32];
    __shared__ unsigned short Wvsh[2 * 64 * 32];
    __shared__ float EsumSh[32];
    const int tid = threadIdx.x, w = tid >> 6, lane = tid & 63;
    const int l15 = lane & 15, quad = lane >> 4;
    const int srow = lane >> 2, scol = (lane & 3) * 8;
    const int bh = blockIdx.x & 63, q = blockIdx.x >> 6;
    const int b = bh >> 4, h = bh & 15;
    const unsigned short* Ex = Exb + ((size_t)b * 2048 + h * 128 + q * 32) * 1024;
    const unsigned short* Wk = Wb + 1048576 + (size_t)h * 64 * 1024;
    const unsigned short* Wv = Wb + 2097152 + (size_t)h * 64 * 1024;
    for (int r = w; r < 32; r += 4) {
        const unsigned short* er = Eb + ((size_t)(h * 128 + q * 32 + r)) * 4096;
        float s = 0.f;
#pragma unroll
        for (int i = 0; i < 8; i++) {
            ushort4 a = *(const ushort4*)&er[i * 512 + lane * 8];
            ushort4 b2 = *(const ushort4*)&er[i * 512 + lane * 8 + 4];
            s += bf2f(a.x) + bf2f(a.y) + bf2f(a.z) + bf2f(a.w);
            s += bf2f(b2.x) + bf2f(b2.y) + bf2f(b2.z) + bf2f(b2.w);
        }
#pragma unroll
        for (int off = 32; off >= 1; off >>= 1) s += __shfl_xor(s, off, 64);
        if (lane == 0) EsumSh[r] = s;
    }
    f32x4 accK[4] = {};
    f32x4 accV[2][2] = {};
    auto STAGE = [&](int t, int s) {
        const int c0 = t * 32;
        if (w < 2)
            gload_lds16(Ex + (size_t)(w * 16 + srow) * 1024 + c0 + scol,
                        (char*)Exsh + s * 2048 + w * 1024);
        gload_lds16(Wk + (size_t)(w * 16 + srow) * 1024 + c0 + scol,
                    (char*)Wksh + s * 4096 + w * 1024);
        gload_lds16(Wv + (size_t)(w * 16 + srow) * 1024 + c0 + scol,
                    (char*)Wvsh + s * 4096 + w * 1024);
    };
    auto COMPUTE = [&](int s) {
        if (w < 2) {
            bf16x8 af = *(const bf16x8*)&Exsh[s * 1024 + (w * 16 + l15) * 32 + quad * 8];
#pragma unroll
            for (int nt = 0; nt < 4; nt++) {
                bf16x8 bb = *(const bf16x8*)&Wksh[s * 2048 + (nt * 16 + l15) * 32 + quad * 8];
                accK[nt] = __builtin_amdgcn_mfma_f32_16x16x32_bf16(af, bb, accK[nt], 0, 0, 0);
            }
        } else {
            bf16x8 av[2], be[2];
#pragma unroll
            for (int mi = 0; mi < 2; mi++)
                av[mi] = *(const bf16x8*)&Wvsh[s * 2048 + (((w - 2) * 2 + mi) * 16 + l15) * 32 + quad * 8];
#pragma unroll
            for (int n = 0; n < 2; n++)
                be[n] = *(const bf16x8*)&Exsh[s * 1024 + (n * 16 + l15) * 32 + quad * 8];
#pragma unroll
            for (int mi = 0; mi < 2; mi++)
#pragma unroll
                for (int n = 0; n < 2; n++)
                    accV[mi][n] = __builtin_amdgcn_mfma_f32_16x16x32_bf16(av[mi], be[n],
                                                                          accV[mi][n], 0, 0, 0);
        }
    };
    STAGE(0, 0);
    __syncthreads();
    for (int t = 0; t < 31; ++t) {
        STAGE(t + 1, (t + 1) & 1);
        COMPUTE(t & 1);
        __syncthreads();
    }
    COMPUTE(1);
    unsigned short* Kp = Kpb + (size_t)bh * 128 * 64;
    unsigned short* VpT = VpTb + (size_t)bh * 64 * 128;
    if (w < 2) {
#pragma unroll
        for (int nt = 0; nt < 4; nt++) {
            int col = nt * 16 + l15;
            float bkv = bk[h * 64 + col];
#pragma unroll
            for (int r = 0; r < 4; r++) {
                int krow = w * 16 + quad * 4 + r;
                Kp[(q * 32 + krow) * 64 + col] = f2bf(accK[nt][r] + EsumSh[krow] * bkv);
            }
        }
    } else {
#pragma unroll
        for (int mi = 0; mi < 2; mi++)
#pragma unroll
            for (int n = 0; n < 2; n++) {
                int kcol = n * 16 + l15;
                float es = EsumSh[kcol];
#pragma unroll
                for (int r = 0; r < 4; r++) {
                    int d = ((w - 2) * 2 + mi) * 16 + quad * 4 + r;
                    VpT[d * 128 + q * 32 + kcol] = f2bf(accV[mi][n][r] + es * bv[h * 64 + d]);
                }
            }
    }
}

// ---------------- fused Q projection + attention ----------------
// Per block: 128x128 Q tile (128 seq rows x heads {2*bx, 2*bx+1}), K=1024 m97 loop.
// Each wave (wm,wn) owns a 64-row x 1-head sub-tile = an independent attention unit.
// r11: Kp B-fragments (rt-invariant, 16KB/head, 64 VGPRs) hoisted out of the
// rt-loop — QK^T is pure register MFMA; Vp stays in-loop (L1-hot after rt=0).
__global__ __launch_bounds__(256) void gemm_qattn(
        const unsigned short* __restrict__ xb, const unsigned short* __restrict__ Wb,
        const float* __restrict__ bq,
        const unsigned short* __restrict__ Kpb, const unsigned short* __restrict__ VpTb,
        float* __restrict__ out) {
    __shared__ __align__(16) unsigned short smem[16384];   // 32,768 B
    unsigned short* lA = smem;
    unsigned short* lB = smem + 8192;
    const int tid = threadIdx.x, w = tid >> 6, lane = tid & 63;
    const int m0 = blockIdx.y * 128, n0 = blockIdx.x * 128;
    const int srow = lane >> 2, scol = (lane & 3) * 8;
    const int l15 = lane & 15, quad = lane >> 4;
    const int wm = w >> 1, wn = w & 1;
    f32x4 acc[4][4] = {};
    for (int k0 = 0; k0 < 1024; k0 += 64) {
        __syncthreads();
#pragma unroll
        for (int s = 0; s < 2; s++) {
#pragma unroll
            for (int i = 0; i < 2; i++) {
                int t = w * 2 + i;
                gload_lds16(xb + (size_t)(m0 + t * 16 + srow) * 1024 + k0 + s * 32 + scol,
                            (char*)lA + (s * 8192 + t * 1024));
                gload_lds16(Wb + (size_t)(n0 + t * 16 + srow) * 1024 + k0 + s * 32 + scol,
                            (char*)lB + (s * 8192 + t * 1024));
            }
        }
        __syncthreads();
#pragma unroll
        for (int s = 0; s < 2; s++) {
            bf16x8 af[4], bfr[4];
#pragma unroll
            for (int mi = 0; mi < 4; mi++)
                af[mi] = *(const bf16x8*)&lA[(s * 128 + wm * 64 + mi * 16 + l15) * 32 + quad * 8];
#pragma unroll
            for (int ni = 0; ni < 4; ni++)
                bfr[ni] = *(const bf16x8*)&lB[(s * 128 + wn * 64 + ni * 16 + l15) * 32 + quad * 8];
#pragma unroll
            for (int mi = 0; mi < 4; mi++)
#pragma unroll
                for (int ni = 0; ni < 4; ni++)
                    acc[mi][ni] = __builtin_amdgcn_mfma_f32_16x16x32_bf16(af[mi], bfr[ni],
                                                                          acc[mi][ni], 0, 0, 0);
        }
    }
    __syncthreads();   // staging dead; smem becomes Qtile[128][128]
    // Q tile (bias added) -> LDS, C layout (row=quad*4+r, col=l15)
#pragma unroll
    for (int ni = 0; ni < 4; ni++) {
        int lc = wn * 64 + ni * 16 + l15;
        float bias_v = bq[n0 + lc];
#pragma unroll
        for (int mi = 0; mi < 4; mi++) {
            int lr = wm * 64 + mi * 16 + quad * 4;
#pragma unroll
            for (int r = 0; r < 4; r++)
                smem[(lr + r) * 128 + lc] = f2bf(acc[mi][ni][r] + bias_v);
        }
    }
    __syncthreads();
    // per-wave Q A-fragments: rows wm*64+rt*16+l15, head cols wn*64 + ds*32 + quad*8
    bf16x8 aq[4][2];
#pragma unroll
    for (int rt = 0; rt < 4; rt++)
#pragma unroll
        for (int ds = 0; ds < 2; ds++)
            aq[rt][ds] = *(const bf16x8*)&smem[(wm * 64 + rt * 16 + l15) * 128 +
                                               wn * 64 + ds * 32 + quad * 8];
    __syncthreads();   // all waves got Q frags; smem becomes per-wave P slabs
    const int b = m0 >> 12;
    const int h = blockIdx.x * 2 + wn;
    const int lbase = (m0 & 4095) + wm * 64;
    const unsigned short* Kp = Kpb + (size_t)(b * 16 + h) * 128 * 64;
    const unsigned short* Vp = VpTb + (size_t)(b * 16 + h) * 64 * 128;
    const float scale = 0.125f;
    unsigned short* slab = smem + w * 2176;   // per-wave private [16][136]
    // hoist Kp B-fragments: identical for every rt (16 x bf16x8 = 64 VGPRs)
    bf16x8 kb0[8], kb1[8];
#pragma unroll
    for (int kt = 0; kt < 8; kt++) {
        const unsigned short* kr = Kp + (size_t)(kt * 16 + l15) * 64;
        kb0[kt] = *(const bf16x8*)&kr[quad * 8];
        kb1[kt] = *(const bf16x8*)&kr[32 + quad * 8];
    }
    f32x4 acco[4][4] = {};   // [rt][nt]
#pragma unroll
    for (int rt = 0; rt < 4; rt++) {
        // QK^T: 16 rows x 128 k — pure register MFMA
        f32x4 sc[8];
#pragma unroll
        for (int kt = 0; kt < 8; kt++) {
            f32x4 a = {};
            a = __builtin_amdgcn_mfma_f32_16x16x32_bf16(aq[rt][0], kb0[kt], a, 0, 0, 0);
            a = __builtin_amdgcn_mfma_f32_16x16x32_bf16(aq[rt][1], kb1[kt], a, 0, 0, 0);
            sc[kt] = a;
        }
        // softmax over 128 cols (kt regs x l15 lanes); in-place into sc
#pragma unroll
        for (int r = 0; r < 4; r++) {
            float m = -1e30f;
#pragma unroll
            for (int kt = 0; kt < 8; kt++) m = fmaxf(m, sc[kt][r]);
#pragma unroll
            for (int off = 8; off >= 1; off >>= 1) m = fmaxf(m, __shfl_xor(m, off, 64));
            float s = 0.f;
#pragma unroll
            for (int kt = 0; kt < 8; kt++) {
                float e = __expf(scale * (sc[kt][r] - m));
                sc[kt][r] = e;
                s += e;
            }
#pragma unroll
            for (int off = 8; off >= 1; off >>= 1) s += __shfl_xor(s, off, 64);
            float rinv = 1.0f / s;
#pragma unroll
            for (int kt = 0; kt < 8; kt++) sc[kt][r] *= rinv;
        }
        // P -> per-wave slab (C layout) -> A-fragments
#pragma unroll
        for (int kt = 0; kt < 8; kt++)
#pragma unroll
            for (int r = 0; r < 4; r++)
                slab[(quad * 4 + r) * 136 + kt * 16 + l15] = f2bf(sc[kt][r]);
        bf16x8 ap[4];
#pragma unroll
        for (int t = 0; t < 4; t++)
            ap[t] = *(const bf16x8*)&slab[l15 * 136 + t * 32 + quad * 8];
        // PV: 16 rows x 64 d (Vp rows L1-hot after rt=0)
#pragma unroll
        for (int nt = 0; nt < 4; nt++) {
            const unsigned short* vr = Vp + (size_t)(nt * 16 + l15) * 128;
#pragma unroll
            for (int t = 0; t < 4; t++) {
                bf16x8 bv = *(const bf16x8*)&vr[t * 32 + quad * 8];
                acco[rt][nt] = __builtin_amdgcn_mfma_f32_16x16x32_bf16(ap[t], bv,
                                                                       acco[rt][nt], 0, 0, 0);
            }
        }
    }
#pragma unroll
    for (int rt = 0; rt < 4; rt++)
#pragma unroll
        for (int nt = 0; nt < 4; nt++) {
            int col = h * 64 + nt * 16 + l15;
#pragma unroll
            for (int r = 0; r < 4; r++)
                out[(size_t)(b * 4096 + lbase + rt * 16 + quad * 4 + r) * 1024 + col] =
                    acco[rt][nt][r];
        }
}

extern "C" void kernel_launch(void* const* d_in, const int* in_sizes, int n_in,
                              void* d_out, int out_size, void* d_ws, size_t ws_size,
                              hipStream_t stream) {
    const float* x  = (const float*)d_in[0];
    const float* Wq = (const float*)d_in[1];
    const float* bq = (const float*)d_in[2];
    const float* Wk = (const float*)d_in[3];
    const float* bk = (const float*)d_in[4];
    const float* Wv = (const float*)d_in[5];
    const float* bv = (const float*)d_in[6];
    const float* E  = (const float*)d_in[7];
    float* out = (float*)d_out;
    char* ws = (char*)d_ws;

    // Alias-free workspace: every byte has exactly one value per call, identical
    // across calls — safe under overlapped graph replays.
    unsigned short* xb   = (unsigned short*)(ws);              // 33,554,432 [b*4096][1024]
    unsigned short* xTb  = (unsigned short*)(ws + 33554432);   // 33,554,432 [b][1024][4096]
    unsigned short* Wb   = (unsigned short*)(ws + 67108864);   //  6,291,456 (Wq|Wk|Wv)
    unsigned short* Eb   = (unsigned short*)(ws + 106954752);  // 16,777,216 [2048][4096]
    unsigned short* Exb  = (unsigned short*)(ws + 123731968);  // 16,777,216 [b][2048][1024]
    unsigned short* Kpb  = (unsigned short*)(ws + 140509184);  //  1,048,576 [bh][128][64]
    unsigned short* VpTb = (unsigned short*)(ws + 141557760);  //  1,048,576 [bh][64][128]
    if (ws_size < 142606336) return;                           // total = 142,606,336

    fused_cvt<<<15360, 256, 0, stream>>>(x, Wq, Wk, Wv, E, xb, xTb, Wb, Eb);
    gemm_ex<<<dim3(8, 16, 4), 256, 0, stream>>>(Eb, xTb, Exb);
    kpvp4<<<256, 256, 0, stream>>>(Exb, Wb, Eb, bk, bv, Kpb, VpTb);
    gemm_qattn<<<dim3(8, 128), 256, 0, stream>>>(xb, Wb, bq, Kpb, VpTb, out);
}